// Round 1
// baseline (720.872 us; speedup 1.0000x reference)
//
#include <hip/hip_runtime.h>
#include <math.h>

#define BATCH   65536
#define IN_DIM  784
#define HID     256
#define LAT     32
#define NPROTO  25

#define BM 64
#define BK 16
#define HSTRIDE 260
#define ZSTRIDE 33
// phase1: As[BK][BM]=1024 + Bs[BK][HID]=4096 = 5120 floats
// phase2: h_lds[32][HSTRIDE]=8320 + z_lds[64][ZSTRIDE]=2112 = 10432 floats
#define SMEM_FLOATS 10432

__global__ __launch_bounds__(256)
void dpsom_encoder(const float* __restrict__ x,
                   const float* __restrict__ We1,
                   const float* __restrict__ be1,
                   const float* __restrict__ We2,
                   const float* __restrict__ be2,
                   const float* __restrict__ protos,
                   float* __restrict__ z_out,
                   float* __restrict__ somz_out,
                   int* __restrict__ minidx_out)
{
    __shared__ float smem[SMEM_FLOATS];
    __shared__ int minidx_lds[BM];
    float* As = smem;                  // [BK][BM]  (A stored k-major, transposed on load)
    float* Bs = smem + BK * BM;        // [BK][HID]
    float* h_lds = smem;               // [32][HSTRIDE] (aliases phase-1 region)
    float* z_lds = smem + 32 * HSTRIDE; // [64][ZSTRIDE]

    const int tid = threadIdx.x;
    const int tx = tid & 31;   // 32 col-groups of 8
    const int ty = tid >> 5;   // 8 row-groups of 8
    const int row0 = blockIdx.x * BM;

    float acc[8][8];
#pragma unroll
    for (int i = 0; i < 8; ++i)
#pragma unroll
        for (int j = 0; j < 8; ++j) acc[i][j] = 0.f;

    const int ar  = tid >> 2;  // 0..63 : A row
    const int akq = tid & 3;   // 0..3  : A k-quad

    for (int k0 = 0; k0 < IN_DIM; k0 += BK) {
        __syncthreads();
        // A tile: x[row0+ar][k0 + akq*4 .. +4] -> As[k][m] (transposed)
        float4 av = *(const float4*)(x + (size_t)(row0 + ar) * IN_DIM + k0 + akq * 4);
        As[(akq * 4 + 0) * BM + ar] = av.x;
        As[(akq * 4 + 1) * BM + ar] = av.y;
        As[(akq * 4 + 2) * BM + ar] = av.z;
        As[(akq * 4 + 3) * BM + ar] = av.w;
        // B tile: We1[k0+k][0..256) fully coalesced float4
#pragma unroll
        for (int i = 0; i < 4; ++i) {
            int f  = tid + i * 256;
            int bk = f >> 6;
            int bn = (f & 63) << 2;
            *(float4*)(Bs + bk * HID + bn) =
                *(const float4*)(We1 + (size_t)(k0 + bk) * HID + bn);
        }
        __syncthreads();
#pragma unroll
        for (int kk = 0; kk < BK; ++kk) {
            float4 a0 = *(const float4*)(As + kk * BM + ty * 8);
            float4 a1 = *(const float4*)(As + kk * BM + ty * 8 + 4);
            float4 b0 = *(const float4*)(Bs + kk * HID + tx * 8);
            float4 b1 = *(const float4*)(Bs + kk * HID + tx * 8 + 4);
            float a[8] = {a0.x, a0.y, a0.z, a0.w, a1.x, a1.y, a1.z, a1.w};
            float b[8] = {b0.x, b0.y, b0.z, b0.w, b1.x, b1.y, b1.z, b1.w};
#pragma unroll
            for (int i = 0; i < 8; ++i)
#pragma unroll
                for (int j = 0; j < 8; ++j)
                    acc[i][j] = fmaf(a[i], b[j], acc[i][j]);
        }
    }

    // bias + ReLU -> h held in acc
    {
        float bias[8];
#pragma unroll
        for (int j = 0; j < 8; ++j) bias[j] = be1[tx * 8 + j];
#pragma unroll
        for (int i = 0; i < 8; ++i)
#pragma unroll
            for (int j = 0; j < 8; ++j)
                acc[i][j] = fmaxf(acc[i][j] + bias[j], 0.f);
    }

    // ---- phase 2: z = h @ We2 + be2, 32 rows per half staged through LDS ----
    const int jz = tid & 31;
    const int rg = tid >> 5;  // 0..7
    const float bz = be2[jz];

    for (int half = 0; half < 2; ++half) {
        __syncthreads();
        if ((ty >> 2) == half) {
            int rb = (ty & 3) * 8;
#pragma unroll
            for (int i = 0; i < 8; ++i) {
                *(float4*)(h_lds + (rb + i) * HSTRIDE + tx * 8) =
                    make_float4(acc[i][0], acc[i][1], acc[i][2], acc[i][3]);
                *(float4*)(h_lds + (rb + i) * HSTRIDE + tx * 8 + 4) =
                    make_float4(acc[i][4], acc[i][5], acc[i][6], acc[i][7]);
            }
        }
        __syncthreads();
        float s0 = bz, s1 = bz, s2 = bz, s3 = bz;
        const float* h0p = h_lds + (rg * 4 + 0) * HSTRIDE;
        const float* h1p = h_lds + (rg * 4 + 1) * HSTRIDE;
        const float* h2p = h_lds + (rg * 4 + 2) * HSTRIDE;
        const float* h3p = h_lds + (rg * 4 + 3) * HSTRIDE;
#pragma unroll 4
        for (int c = 0; c < HID; c += 4) {
            float w0 = We2[(c + 0) * LAT + jz];
            float w1 = We2[(c + 1) * LAT + jz];
            float w2 = We2[(c + 2) * LAT + jz];
            float w3 = We2[(c + 3) * LAT + jz];
            float4 h0 = *(const float4*)(h0p + c);
            float4 h1 = *(const float4*)(h1p + c);
            float4 h2 = *(const float4*)(h2p + c);
            float4 h3 = *(const float4*)(h3p + c);
            s0 = fmaf(h0.x, w0, fmaf(h0.y, w1, fmaf(h0.z, w2, fmaf(h0.w, w3, s0))));
            s1 = fmaf(h1.x, w0, fmaf(h1.y, w1, fmaf(h1.z, w2, fmaf(h1.w, w3, s1))));
            s2 = fmaf(h2.x, w0, fmaf(h2.y, w1, fmaf(h2.z, w2, fmaf(h2.w, w3, s2))));
            s3 = fmaf(h3.x, w0, fmaf(h3.y, w1, fmaf(h3.z, w2, fmaf(h3.w, w3, s3))));
        }
        int rbase = half * 32 + rg * 4;
        z_lds[(rbase + 0) * ZSTRIDE + jz] = s0;
        z_lds[(rbase + 1) * ZSTRIDE + jz] = s1;
        z_lds[(rbase + 2) * ZSTRIDE + jz] = s2;
        z_lds[(rbase + 3) * ZSTRIDE + jz] = s3;
        z_out[(size_t)(row0 + rbase + 0) * LAT + jz] = s0;
        z_out[(size_t)(row0 + rbase + 1) * LAT + jz] = s1;
        z_out[(size_t)(row0 + rbase + 2) * LAT + jz] = s2;
        z_out[(size_t)(row0 + rbase + 3) * LAT + jz] = s3;
    }
    __syncthreads();

    // ---- phase 3: SOM argmin (reference formula: |z|^2 - 2 z.p + |p|^2) ----
    if (tid < BM) {
        float zr[LAT];
        float zn = 0.f;
#pragma unroll
        for (int j = 0; j < LAT; ++j) {
            zr[j] = z_lds[tid * ZSTRIDE + j];
            zn = fmaf(zr[j], zr[j], zn);
        }
        float best = 3.4e38f;
        int bp = 0;
        for (int p = 0; p < NPROTO; ++p) {
            float dot = 0.f, pn = 0.f;
#pragma unroll
            for (int j = 0; j < LAT; ++j) {
                float pv = protos[p * LAT + j];
                dot = fmaf(zr[j], pv, dot);
                pn  = fmaf(pv, pv, pn);
            }
            float d = zn - 2.f * dot + pn;
            if (d < best) { best = d; bp = p; }  // strict < => first-min (np semantics)
        }
        minidx_out[row0 + tid] = bp;
        minidx_lds[tid] = bp;
    }
    __syncthreads();

    // som_z gather, coalesced across jz
#pragma unroll
    for (int m = 0; m < 8; ++m) {
        int r = rg * 8 + m;
        somz_out[(size_t)(row0 + r) * LAT + jz] = protos[minidx_lds[r] * LAT + jz];
    }
}

// decoder applied to the 25 prototypes only: table[p] = sigmoid(relu(p@Wd1+bd1)@Wd2+bd2)
__global__ __launch_bounds__(256)
void dpsom_dectab(const float* __restrict__ protos,
                  const float* __restrict__ Wd1,
                  const float* __restrict__ bd1,
                  const float* __restrict__ Wd2,
                  const float* __restrict__ bd2,
                  float* __restrict__ table)
{
    __shared__ float pr[LAT];
    __shared__ float hd[HID];
    const int p = blockIdx.x;
    const int tid = threadIdx.x;
    if (tid < LAT) pr[tid] = protos[p * LAT + tid];
    __syncthreads();
    float s = bd1[tid];
#pragma unroll
    for (int k = 0; k < LAT; ++k)
        s = fmaf(pr[k], Wd1[k * HID + tid], s);
    hd[tid] = fmaxf(s, 0.f);
    __syncthreads();
    for (int i = tid; i < IN_DIM; i += 256) {
        float o = bd2[i];
        for (int j = 0; j < HID; ++j)
            o = fmaf(hd[j], Wd2[(size_t)j * IN_DIM + i], o);
        table[p * IN_DIM + i] = 1.f / (1.f + expf(-o));
    }
}

// x_recon[row] = table[minidx[row]]  (float4, fully coalesced writes)
__global__ __launch_bounds__(256)
void dpsom_gather(const float4* __restrict__ table,
                  const int* __restrict__ minidx,
                  float4* __restrict__ xrec)
{
    const int f = blockIdx.x * 256 + threadIdx.x;  // < 65536*196 = 12,845,056
    const int row = f / 196;
    const int c4  = f - row * 196;
    const int idx = minidx[row];
    xrec[f] = table[idx * 196 + c4];
}

extern "C" void kernel_launch(void* const* d_in, const int* in_sizes, int n_in,
                              void* d_out, int out_size, void* d_ws, size_t ws_size,
                              hipStream_t stream)
{
    const float* x    = (const float*)d_in[0];
    const float* We1  = (const float*)d_in[1];
    const float* be1  = (const float*)d_in[2];
    const float* We2  = (const float*)d_in[3];
    const float* be2  = (const float*)d_in[4];
    const float* Wd1  = (const float*)d_in[5];
    const float* bd1  = (const float*)d_in[6];
    const float* Wd2  = (const float*)d_in[7];
    const float* bd2  = (const float*)d_in[8];
    const float* prot = (const float*)d_in[9];

    float* out   = (float*)d_out;
    float* xrec  = out;                                  // [BATCH, 784]
    float* z_out = out + (size_t)BATCH * IN_DIM;         // [BATCH, 32]
    float* somz  = z_out + (size_t)BATCH * LAT;          // [BATCH, 32]

    int*   minidx = (int*)d_ws;                                    // BATCH ints
    float* table  = (float*)((char*)d_ws + (size_t)BATCH * 4);     // 25*784 floats

    hipLaunchKernelGGL(dpsom_encoder, dim3(BATCH / BM), dim3(256), 0, stream,
                       x, We1, be1, We2, be2, prot, z_out, somz, minidx);
    hipLaunchKernelGGL(dpsom_dectab, dim3(NPROTO), dim3(256), 0, stream,
                       prot, Wd1, bd1, Wd2, bd2, table);
    hipLaunchKernelGGL(dpsom_gather, dim3((BATCH * (IN_DIM / 4)) / 256), dim3(256), 0, stream,
                       (const float4*)table, minidx, (float4*)xrec);
}

// Round 2
// 512.315 us; speedup vs baseline: 1.4071x; 1.4071x over previous
//
#include <hip/hip_runtime.h>
#include <hip/hip_bf16.h>
#include <math.h>

#define BATCH   65536
#define IN_DIM  784
#define HID     256
#define LAT     32
#define NPROTO  25

typedef short  short8  __attribute__((ext_vector_type(8)));
typedef float  floatx4 __attribute__((ext_vector_type(4)));

// ---------------- bf16 split helpers ----------------
__device__ __forceinline__ unsigned short f2bf(float v) {
    __hip_bfloat16 b = __float2bfloat16(v);
    return *reinterpret_cast<unsigned short*>(&b);
}
__device__ __forceinline__ float bf2f(unsigned short u) {
    __hip_bfloat16 b = *reinterpret_cast<__hip_bfloat16*>(&u);
    return __bfloat162float(b);
}
__device__ __forceinline__ void split3(float v, unsigned short& o1,
                                       unsigned short& o2, unsigned short& o3) {
    o1 = f2bf(v); float r1 = v - bf2f(o1);
    o2 = f2bf(r1); float r2 = r1 - bf2f(o2);
    o3 = f2bf(r2);
}

__device__ __forceinline__ floatx4 mm_bf16(short8 a, short8 b, floatx4 c) {
    return __builtin_amdgcn_mfma_f32_16x16x32_bf16(a, b, c, 0, 0, 0);
}

__device__ __forceinline__ void async_copy16(const void* g, void* l) {
    __builtin_amdgcn_global_load_lds(
        (const __attribute__((address_space(1))) unsigned int*)g,
        (__attribute__((address_space(3))) unsigned int*)l, 16, 0, 0);
}

// ================= MFMA path =================
// ws layout: Bt1 @0, Bt2 @409600, Bt3 @819200  (each [25][256][32] bf16, chunk-swizzled)
//            table @1228800 (25*784 f32)
#define BT_BYTES   409600
#define WS_NEEDED  1307200

// prep: We1[784][256] f32 -> 3 split arrays, layout [step][n][k] bf16, K padded to 800,
// 16B chunks within each 64B row XOR-swizzled by ((n>>1)&3).
__global__ __launch_bounds__(256)
void prep_B(const float* __restrict__ We1,
            unsigned short* __restrict__ B1,
            unsigned short* __restrict__ B2,
            unsigned short* __restrict__ B3)
{
    int e = (blockIdx.x * 256 + threadIdx.x) * 4;  // 25*256*32 = 204800 elements
    int k = e & 31;
    int n = (e >> 5) & 255;
    int s = e >> 13;
    int cs = (k >> 3) ^ ((n >> 1) & 3);
    int dst = (s * 256 + n) * 32 + cs * 8 + (k & 7);
    ushort4 u1, u2, u3;
    unsigned short a, b, c;
#pragma unroll
    for (int j = 0; j < 4; ++j) {
        int kk = s * 32 + k + j;
        float v = (kk < IN_DIM) ? We1[(size_t)kk * HID + n] : 0.f;
        split3(v, a, b, c);
        ((unsigned short*)&u1)[j] = a;
        ((unsigned short*)&u2)[j] = b;
        ((unsigned short*)&u3)[j] = c;
    }
    *(ushort4*)(B1 + dst) = u1;
    *(ushort4*)(B2 + dst) = u2;
    *(ushort4*)(B3 + dst) = u3;
}

// decoder table: table[p] = sigmoid(relu(p@Wd1+bd1)@Wd2+bd2)   (25 rows only)
__global__ __launch_bounds__(256)
void dpsom_dectab(const float* __restrict__ protos,
                  const float* __restrict__ Wd1,
                  const float* __restrict__ bd1,
                  const float* __restrict__ Wd2,
                  const float* __restrict__ bd2,
                  float* __restrict__ table)
{
    __shared__ float pr[LAT];
    __shared__ float hd[HID];
    const int p = blockIdx.x;
    const int tid = threadIdx.x;
    if (tid < LAT) pr[tid] = protos[p * LAT + tid];
    __syncthreads();
    float s = bd1[tid];
#pragma unroll
    for (int k = 0; k < LAT; ++k)
        s = fmaf(pr[k], Wd1[k * HID + tid], s);
    hd[tid] = fmaxf(s, 0.f);
    __syncthreads();
    for (int i = tid; i < IN_DIM; i += 256) {
        float o = bd2[i];
        for (int j = 0; j < HID; ++j)
            o = fmaf(hd[j], Wd2[(size_t)j * IN_DIM + i], o);
        table[p * IN_DIM + i] = 1.f / (1.f + expf(-o));
    }
}

// fused encoder: x -> (MFMA split-bf16) h -> z -> argmin -> som_z, z, x_recon(table gather)
// LDS: A1@0 A2@4096 A3@8192 (each [64][32] bf16, swizzled)
//      B1@12288 B2@28672 B3@45056 (each [256][32] bf16, swizzled)  total 60KB
// epilogue aliases: h_lds(f32[32][260])@0, z_lds(f32[64][33])@33280, minidx@41728
__global__ __launch_bounds__(256, 2)
void dpsom_encoder_mfma(const float* __restrict__ x,
                        const unsigned short* __restrict__ B1g,
                        const unsigned short* __restrict__ B2g,
                        const unsigned short* __restrict__ B3g,
                        const float* __restrict__ be1,
                        const float* __restrict__ We2,
                        const float* __restrict__ be2,
                        const float* __restrict__ protos,
                        const float* __restrict__ table,
                        float* __restrict__ z_out,
                        float* __restrict__ somz_out,
                        float* __restrict__ xrec)
{
    __shared__ __align__(16) char smem[61440];
    const int tid  = threadIdx.x;
    const int wave = tid >> 6;
    const int lane = tid & 63;
    const int l15  = lane & 15;
    const int q    = lane >> 4;
    const int sw   = (l15 >> 1) & 3;      // XOR chunk swizzle
    const int row0 = blockIdx.x * 64;

    floatx4 acc[4][4];
#pragma unroll
    for (int i = 0; i < 4; ++i)
#pragma unroll
        for (int j = 0; j < 4; ++j) acc[i][j] = (floatx4)0.f;

    for (int s = 0; s < 25; ++s) {
        __syncthreads();
        // ---- stage B (3 arrays, 16KB each) via global_load_lds width=16 ----
        {
            size_t gbase = (size_t)s * 16384 + (size_t)wave * 4096 + (size_t)lane * 16;
            char* lb = smem + 12288 + wave * 4096 + lane * 16;
#pragma unroll
            for (int i = 0; i < 4; ++i) {
                async_copy16((const char*)B1g + gbase + i * 1024, lb + 0     + i * 1024);
                async_copy16((const char*)B2g + gbase + i * 1024, lb + 16384 + i * 1024);
                async_copy16((const char*)B3g + gbase + i * 1024, lb + 32768 + i * 1024);
            }
        }
        // ---- stage A: 64x32 f32 tile, convert to 3x bf16, swizzled ds_write ----
#pragma unroll
        for (int i = 0; i < 2; ++i) {
            int ff  = tid + i * 256;          // 0..511
            int row = ff >> 3;
            int k4  = ff & 7;
            float4 v = make_float4(0.f, 0.f, 0.f, 0.f);
            if (s < 24 || k4 < 4)
                v = *(const float4*)(x + (size_t)(row0 + row) * IN_DIM + s * 32 + k4 * 4);
            ushort4 u1, u2, u3;
            unsigned short a, b, c;
            split3(v.x, a, b, c); u1.x = a; u2.x = b; u3.x = c;
            split3(v.y, a, b, c); u1.y = a; u2.y = b; u3.y = c;
            split3(v.z, a, b, c); u1.z = a; u2.z = b; u3.z = c;
            split3(v.w, a, b, c); u1.w = a; u2.w = b; u3.w = c;
            int csw = ((k4 >> 1) ^ ((row >> 1) & 3));
            int dst = row * 64 + csw * 16 + (k4 & 1) * 8;
            *(ushort4*)(smem + dst)        = u1;
            *(ushort4*)(smem + 4096 + dst) = u2;
            *(ushort4*)(smem + 8192 + dst) = u3;
        }
        __syncthreads();

        // ---- compute ----
        short8 afr[3][4];
#pragma unroll
        for (int mf = 0; mf < 4; ++mf) {
            int abyte = (16 * mf + l15) * 64 + ((q ^ sw) * 16);
            afr[0][mf] = *(short8*)(smem + abyte);
            afr[1][mf] = *(short8*)(smem + 4096 + abyte);
            afr[2][mf] = *(short8*)(smem + 8192 + abyte);
        }
#pragma unroll
        for (int nf = 0; nf < 4; ++nf) {
            int n = wave * 64 + 16 * nf + l15;
            int bbyte = n * 64 + ((q ^ sw) * 16);
            short8 b1 = *(short8*)(smem + 12288 + bbyte);
            short8 b2 = *(short8*)(smem + 28672 + bbyte);
            short8 b3 = *(short8*)(smem + 45056 + bbyte);
#pragma unroll
            for (int mf = 0; mf < 4; ++mf) {
                floatx4 t = acc[mf][nf];
                t = mm_bf16(afr[0][mf], b1, t);
                t = mm_bf16(afr[0][mf], b2, t);
                t = mm_bf16(afr[1][mf], b1, t);
                t = mm_bf16(afr[1][mf], b2, t);
                t = mm_bf16(afr[0][mf], b3, t);
                t = mm_bf16(afr[2][mf], b1, t);
                acc[mf][nf] = t;
            }
        }
    }

    // bias + ReLU (h held in acc; C layout: row=16mf+4q+r, col=wave*64+16nf+l15)
    {
        float bias[4];
#pragma unroll
        for (int nf = 0; nf < 4; ++nf) bias[nf] = be1[wave * 64 + 16 * nf + l15];
#pragma unroll
        for (int mf = 0; mf < 4; ++mf)
#pragma unroll
            for (int nf = 0; nf < 4; ++nf)
#pragma unroll
                for (int r = 0; r < 4; ++r)
                    acc[mf][nf][r] = fmaxf(acc[mf][nf][r] + bias[nf], 0.f);
    }

    float* h_lds = (float*)smem;              // [32][260]
    float* z_lds = (float*)(smem + 33280);    // [64][33]
    int*  minidx = (int*)(smem + 41728);      // [64]

    const int jz = tid & 31;
    const int rg = tid >> 5;
    const float bz = be2[jz];

    for (int half = 0; half < 2; ++half) {
        __syncthreads();
#pragma unroll
        for (int mm = 0; mm < 2; ++mm) {
            int mf = 2 * half + mm;
#pragma unroll
            for (int nf = 0; nf < 4; ++nf)
#pragma unroll
                for (int r = 0; r < 4; ++r) {
                    int lr = 16 * mm + 4 * q + r;
                    h_lds[lr * 260 + wave * 64 + 16 * nf + l15] = acc[mf][nf][r];
                }
        }
        __syncthreads();
        float s0 = bz, s1 = bz, s2 = bz, s3 = bz;
        const float* h0p = h_lds + (rg * 4 + 0) * 260;
        const float* h1p = h_lds + (rg * 4 + 1) * 260;
        const float* h2p = h_lds + (rg * 4 + 2) * 260;
        const float* h3p = h_lds + (rg * 4 + 3) * 260;
#pragma unroll 4
        for (int c = 0; c < HID; c += 4) {
            float w0 = We2[(c + 0) * LAT + jz];
            float w1 = We2[(c + 1) * LAT + jz];
            float w2 = We2[(c + 2) * LAT + jz];
            float w3 = We2[(c + 3) * LAT + jz];
            float4 h0 = *(const float4*)(h0p + c);
            float4 h1 = *(const float4*)(h1p + c);
            float4 h2 = *(const float4*)(h2p + c);
            float4 h3 = *(const float4*)(h3p + c);
            s0 = fmaf(h0.x, w0, fmaf(h0.y, w1, fmaf(h0.z, w2, fmaf(h0.w, w3, s0))));
            s1 = fmaf(h1.x, w0, fmaf(h1.y, w1, fmaf(h1.z, w2, fmaf(h1.w, w3, s1))));
            s2 = fmaf(h2.x, w0, fmaf(h2.y, w1, fmaf(h2.z, w2, fmaf(h2.w, w3, s2))));
            s3 = fmaf(h3.x, w0, fmaf(h3.y, w1, fmaf(h3.z, w2, fmaf(h3.w, w3, s3))));
        }
        int rbase = half * 32 + rg * 4;
        z_lds[(rbase + 0) * 33 + jz] = s0;
        z_lds[(rbase + 1) * 33 + jz] = s1;
        z_lds[(rbase + 2) * 33 + jz] = s2;
        z_lds[(rbase + 3) * 33 + jz] = s3;
        z_out[(size_t)(row0 + rbase + 0) * LAT + jz] = s0;
        z_out[(size_t)(row0 + rbase + 1) * LAT + jz] = s1;
        z_out[(size_t)(row0 + rbase + 2) * LAT + jz] = s2;
        z_out[(size_t)(row0 + rbase + 3) * LAT + jz] = s3;
    }
    __syncthreads();

    // argmin over 25 prototypes (reference formula, strict < = first-min)
    if (tid < 64) {
        float zr[LAT];
        float zn = 0.f;
#pragma unroll
        for (int j = 0; j < LAT; ++j) {
            zr[j] = z_lds[tid * 33 + j];
            zn = fmaf(zr[j], zr[j], zn);
        }
        float best = 3.4e38f;
        int bp = 0;
        for (int p = 0; p < NPROTO; ++p) {
            float dot = 0.f, pn = 0.f;
#pragma unroll
            for (int j = 0; j < LAT; ++j) {
                float pv = protos[p * LAT + j];
                dot = fmaf(zr[j], pv, dot);
                pn  = fmaf(pv, pv, pn);
            }
            float d = zn - 2.f * dot + pn;
            if (d < best) { best = d; bp = p; }
        }
        minidx[tid] = bp;
    }
    __syncthreads();

    // som_z gather
#pragma unroll
    for (int m = 0; m < 8; ++m) {
        int r = rg * 8 + m;
        somz_out[(size_t)(row0 + r) * LAT + jz] = protos[minidx[r] * LAT + jz];
    }

    // fused x_recon: rows from decoder table (L2-hot), coalesced float4 stores
    for (int i2 = tid; i2 < 64 * 196; i2 += 256) {
        int row = i2 / 196;
        int c   = i2 - row * 196;
        int idx = minidx[row];
        ((float4*)xrec)[(size_t)(row0 + row) * 196 + c] =
            ((const float4*)table)[idx * 196 + c];
    }
}

// ================= fallback fp32 path (round-1, passed) =================
#define BMf 64
#define BKf 16
#define HSTRIDE 260
#define ZSTRIDE 33
#define SMEM_FLOATS 10432

__global__ __launch_bounds__(256)
void dpsom_encoder_fp32(const float* __restrict__ x,
                        const float* __restrict__ We1,
                        const float* __restrict__ be1,
                        const float* __restrict__ We2,
                        const float* __restrict__ be2,
                        const float* __restrict__ protos,
                        float* __restrict__ z_out,
                        float* __restrict__ somz_out,
                        int* __restrict__ minidx_out)
{
    __shared__ float smem[SMEM_FLOATS];
    __shared__ int minidx_lds[BMf];
    float* As = smem;
    float* Bs = smem + BKf * BMf;
    float* h_lds = smem;
    float* z_lds = smem + 32 * HSTRIDE;

    const int tid = threadIdx.x;
    const int tx = tid & 31;
    const int ty = tid >> 5;
    const int row0 = blockIdx.x * BMf;

    float acc[8][8];
#pragma unroll
    for (int i = 0; i < 8; ++i)
#pragma unroll
        for (int j = 0; j < 8; ++j) acc[i][j] = 0.f;

    const int ar  = tid >> 2;
    const int akq = tid & 3;

    for (int k0 = 0; k0 < IN_DIM; k0 += BKf) {
        __syncthreads();
        float4 av = *(const float4*)(x + (size_t)(row0 + ar) * IN_DIM + k0 + akq * 4);
        As[(akq * 4 + 0) * BMf + ar] = av.x;
        As[(akq * 4 + 1) * BMf + ar] = av.y;
        As[(akq * 4 + 2) * BMf + ar] = av.z;
        As[(akq * 4 + 3) * BMf + ar] = av.w;
#pragma unroll
        for (int i = 0; i < 4; ++i) {
            int f  = tid + i * 256;
            int bk = f >> 6;
            int bn = (f & 63) << 2;
            *(float4*)(Bs + bk * HID + bn) =
                *(const float4*)(We1 + (size_t)(k0 + bk) * HID + bn);
        }
        __syncthreads();
#pragma unroll
        for (int kk = 0; kk < BKf; ++kk) {
            float4 a0 = *(const float4*)(As + kk * BMf + ty * 8);
            float4 a1 = *(const float4*)(As + kk * BMf + ty * 8 + 4);
            float4 b0 = *(const float4*)(Bs + kk * HID + tx * 8);
            float4 b1 = *(const float4*)(Bs + kk * HID + tx * 8 + 4);
            float a[8] = {a0.x, a0.y, a0.z, a0.w, a1.x, a1.y, a1.z, a1.w};
            float b[8] = {b0.x, b0.y, b0.z, b0.w, b1.x, b1.y, b1.z, b1.w};
#pragma unroll
            for (int i = 0; i < 8; ++i)
#pragma unroll
                for (int j = 0; j < 8; ++j)
                    acc[i][j] = fmaf(a[i], b[j], acc[i][j]);
        }
    }
    {
        float bias[8];
#pragma unroll
        for (int j = 0; j < 8; ++j) bias[j] = be1[tx * 8 + j];
#pragma unroll
        for (int i = 0; i < 8; ++i)
#pragma unroll
            for (int j = 0; j < 8; ++j)
                acc[i][j] = fmaxf(acc[i][j] + bias[j], 0.f);
    }
    const int jz = tid & 31;
    const int rg = tid >> 5;
    const float bz = be2[jz];
    for (int half = 0; half < 2; ++half) {
        __syncthreads();
        if ((ty >> 2) == half) {
            int rb = (ty & 3) * 8;
#pragma unroll
            for (int i = 0; i < 8; ++i) {
                *(float4*)(h_lds + (rb + i) * HSTRIDE + tx * 8) =
                    make_float4(acc[i][0], acc[i][1], acc[i][2], acc[i][3]);
                *(float4*)(h_lds + (rb + i) * HSTRIDE + tx * 8 + 4) =
                    make_float4(acc[i][4], acc[i][5], acc[i][6], acc[i][7]);
            }
        }
        __syncthreads();
        float s0 = bz, s1 = bz, s2 = bz, s3 = bz;
        const float* h0p = h_lds + (rg * 4 + 0) * HSTRIDE;
        const float* h1p = h_lds + (rg * 4 + 1) * HSTRIDE;
        const float* h2p = h_lds + (rg * 4 + 2) * HSTRIDE;
        const float* h3p = h_lds + (rg * 4 + 3) * HSTRIDE;
#pragma unroll 4
        for (int c = 0; c < HID; c += 4) {
            float w0 = We2[(c + 0) * LAT + jz];
            float w1 = We2[(c + 1) * LAT + jz];
            float w2 = We2[(c + 2) * LAT + jz];
            float w3 = We2[(c + 3) * LAT + jz];
            float4 h0 = *(const float4*)(h0p + c);
            float4 h1 = *(const float4*)(h1p + c);
            float4 h2 = *(const float4*)(h2p + c);
            float4 h3 = *(const float4*)(h3p + c);
            s0 = fmaf(h0.x, w0, fmaf(h0.y, w1, fmaf(h0.z, w2, fmaf(h0.w, w3, s0))));
            s1 = fmaf(h1.x, w0, fmaf(h1.y, w1, fmaf(h1.z, w2, fmaf(h1.w, w3, s1))));
            s2 = fmaf(h2.x, w0, fmaf(h2.y, w1, fmaf(h2.z, w2, fmaf(h2.w, w3, s2))));
            s3 = fmaf(h3.x, w0, fmaf(h3.y, w1, fmaf(h3.z, w2, fmaf(h3.w, w3, s3))));
        }
        int rbase = half * 32 + rg * 4;
        z_lds[(rbase + 0) * ZSTRIDE + jz] = s0;
        z_lds[(rbase + 1) * ZSTRIDE + jz] = s1;
        z_lds[(rbase + 2) * ZSTRIDE + jz] = s2;
        z_lds[(rbase + 3) * ZSTRIDE + jz] = s3;
        z_out[(size_t)(row0 + rbase + 0) * LAT + jz] = s0;
        z_out[(size_t)(row0 + rbase + 1) * LAT + jz] = s1;
        z_out[(size_t)(row0 + rbase + 2) * LAT + jz] = s2;
        z_out[(size_t)(row0 + rbase + 3) * LAT + jz] = s3;
    }
    __syncthreads();
    if (tid < BMf) {
        float zr[LAT];
        float zn = 0.f;
#pragma unroll
        for (int j = 0; j < LAT; ++j) {
            zr[j] = z_lds[tid * ZSTRIDE + j];
            zn = fmaf(zr[j], zr[j], zn);
        }
        float best = 3.4e38f;
        int bp = 0;
        for (int p = 0; p < NPROTO; ++p) {
            float dot = 0.f, pn = 0.f;
#pragma unroll
            for (int j = 0; j < LAT; ++j) {
                float pv = protos[p * LAT + j];
                dot = fmaf(zr[j], pv, dot);
                pn  = fmaf(pv, pv, pn);
            }
            float d = zn - 2.f * dot + pn;
            if (d < best) { best = d; bp = p; }
        }
        minidx_out[row0 + tid] = bp;
        minidx_lds[tid] = bp;
    }
    __syncthreads();
#pragma unroll
    for (int m = 0; m < 8; ++m) {
        int r = rg * 8 + m;
        somz_out[(size_t)(row0 + r) * LAT + jz] = protos[minidx_lds[r] * LAT + jz];
    }
}

__global__ __launch_bounds__(256)
void dpsom_gather(const float4* __restrict__ table,
                  const int* __restrict__ minidx,
                  float4* __restrict__ xrec)
{
    const int f = blockIdx.x * 256 + threadIdx.x;
    const int row = f / 196;
    const int c4  = f - row * 196;
    const int idx = minidx[row];
    xrec[f] = table[idx * 196 + c4];
}

// ================= launch =================
extern "C" void kernel_launch(void* const* d_in, const int* in_sizes, int n_in,
                              void* d_out, int out_size, void* d_ws, size_t ws_size,
                              hipStream_t stream)
{
    const float* x    = (const float*)d_in[0];
    const float* We1  = (const float*)d_in[1];
    const float* be1  = (const float*)d_in[2];
    const float* We2  = (const float*)d_in[3];
    const float* be2  = (const float*)d_in[4];
    const float* Wd1  = (const float*)d_in[5];
    const float* bd1  = (const float*)d_in[6];
    const float* Wd2  = (const float*)d_in[7];
    const float* bd2  = (const float*)d_in[8];
    const float* prot = (const float*)d_in[9];

    float* out   = (float*)d_out;
    float* xrec  = out;
    float* z_out = out + (size_t)BATCH * IN_DIM;
    float* somz  = z_out + (size_t)BATCH * LAT;

    if (ws_size >= WS_NEEDED) {
        unsigned short* B1 = (unsigned short*)d_ws;
        unsigned short* B2 = (unsigned short*)((char*)d_ws + BT_BYTES);
        unsigned short* B3 = (unsigned short*)((char*)d_ws + 2 * BT_BYTES);
        float* table = (float*)((char*)d_ws + 3 * BT_BYTES);

        hipLaunchKernelGGL(prep_B, dim3(200), dim3(256), 0, stream, We1, B1, B2, B3);
        hipLaunchKernelGGL(dpsom_dectab, dim3(NPROTO), dim3(256), 0, stream,
                           prot, Wd1, bd1, Wd2, bd2, table);
        hipLaunchKernelGGL(dpsom_encoder_mfma, dim3(BATCH / 64), dim3(256), 0, stream,
                           x, B1, B2, B3, be1, We2, be2, prot, table,
                           z_out, somz, xrec);
    } else {
        int*   minidx = (int*)d_ws;
        float* table  = (float*)((char*)d_ws + (size_t)BATCH * 4);
        hipLaunchKernelGGL(dpsom_encoder_fp32, dim3(BATCH / BMf), dim3(256), 0, stream,
                           x, We1, be1, We2, be2, prot, z_out, somz, minidx);
        hipLaunchKernelGGL(dpsom_dectab, dim3(NPROTO), dim3(256), 0, stream,
                           prot, Wd1, bd1, Wd2, bd2, table);
        hipLaunchKernelGGL(dpsom_gather, dim3((BATCH * (IN_DIM / 4)) / 256), dim3(256), 0, stream,
                           (const float4*)table, minidx, (float4*)xrec);
    }
}